// Round 4
// baseline (430.783 us; speedup 1.0000x reference)
//
#include <hip/hip_runtime.h>
#include <hip/hip_bf16.h>
#include <math.h>

#define L_SEQ 8192
#define DM 1024
#define DI 2048
#define NH 32
#define HD 64
#define DS 128
#define CDIM 2304
#define DPROJ 4384
#define NPAD_IN 4608  // 18*256, zero-padded W_in rows
#define KSPLIT 16
#define OPROWS 2176   // 2048 Vs^T rows + 128 B^T rows

typedef short bf16x8 __attribute__((ext_vector_type(8)));
typedef float floatx4 __attribute__((ext_vector_type(4)));
typedef unsigned short u16x4 __attribute__((ext_vector_type(4)));
typedef unsigned short u16x8 __attribute__((ext_vector_type(8)));

#define AS1(p) ((const __attribute__((address_space(1))) void*)(p))
#define AS3(p) ((__attribute__((address_space(3))) void*)(p))

__device__ __forceinline__ float bf2f(unsigned short u) {
  union { unsigned int i; float f; } c; c.i = ((unsigned int)u) << 16; return c.f;
}
__device__ __forceinline__ unsigned short f2bf(float f) {
  return __bfloat16_as_ushort(__float2bfloat16(f));
}

// ---------------------------------------------------------------------------
// 128x256-tile "ring" bf16 GEMM, 64 KB LDS -> 2 blocks/CU (the r4 lever).
// Rationale (r3 post-mortem): at 1 block/CU all waves are barrier-locked into
// the same phase, so ds_read bursts and MFMA clusters serialize (~12.5
// cyc/MFMA vs 4.85 ideal). m114/m97: co-resident blocks overlap pipes fully.
// So: shrink LDS to 64 KB and run 2 independent blocks per CU.
// C[m,n] = sum_k A[m,k]*B[n,k]. 512 thr = 8 waves (2M x 4N), per-wave 64x64,
// BK=64, NT=K/64 (NT>=2).
// LDS 64 KB: A[2buf][128][64] (16KB each) + B[1buf][2grp][128][64] (32KB).
//   B grp g holds n-rows ((rloc>>5)<<6)|(g<<5)|(rloc&31): g0 feeds frags n0-1,
//   g1 feeds n2-3 (per wn quarter).
// Swizzle (rule #21 both-sides): byte ^= ((byte>>7)&7)<<4 within each 16KB
//   group; LDS dest LINEAR (gload_lds constraint), involution applied to the
//   per-lane GLOBAL source and again on the ds_read addr (conflict-free b128).
// Schedule per kt (A buf=kt&1), 2 phases; B slots ping-pong inside the kt:
//   P1: read A[buf](8)+B.g0(4); stage Bg1[kt] then A[kt+1];
//       lgkm(8); bar; lgkm(0); prio1; 16 MFMA n0-1; prio0;
//       vmcnt(2) (drain Bg1[kt], keep A[kt+1]); bar
//   P2: read B.g1(4); stage Bg0[kt+1]; bar; lgkm(0);
//       prio1; 16 MFMA n2-3; prio0; vmcnt(0); bar
// Slot-hazard ledger:
//   Bg1[kt] overwrites kt-1, last read P2(kt-1) -> 2 barriers earlier. SAFE.
//   A[kt+1] overwrites kt-1, last read P2(kt-1). SAFE.
//   Bg0[kt+1] overwrites kt, last read P1(kt) pre-mid-bar. SAFE.
//   vmcnt ledger: entering P1: 0 outstanding. P1 issues Bg1(2)+A(2) ->
//   vmcnt(2) drains Bg1 (and anything older). P2 issues Bg0(2) ->
//   vmcnt(0) drains A[kt+1]+Bg0[kt+1] (both read in P1(kt+1)).
//   Tail: stage guards skip; P1 end uses vmcnt(0) when no A staged.
// The 1-phase prefetch gap on B stalls ~latency-minus-phase; the co-resident
// second block fills it (that is the point of this kernel).
// OMODE 0: bf16 out via LDS repack (64KB, after __syncthreads), Nstore guard.
// OMODE 1: f32 out, direct frag stores.
// ---------------------------------------------------------------------------
template <int OMODE>
__global__ __launch_bounds__(512, 4)
void gemm128_ring(const unsigned short* __restrict__ A, int lda,
                  const unsigned short* __restrict__ B, int ldb,
                  void* __restrict__ Cout, int ldc,
                  int K, int Nstore) {
  __shared__ __align__(16) char lds[65536];
  const int t = threadIdx.x;
  const int lane = t & 63;
  const int w = t >> 6;
  const int wm = w & 1, wn = w >> 1;
  const int fr = lane & 15, quad = lane >> 4;

  // bijective XCD swizzle: xcd owns a contiguous m-band, m-fastest within n
  int gx = gridDim.x, gy = gridDim.y;
  int linear = blockIdx.y * gx + blockIdx.x;
  int xcd = linear & 7, loc = linear >> 3;
  int mper = gy >> 3;                       // gy must be %8==0 (64 here)
  int mt = xcd * mper + loc % mper;
  int nt = loc / mper;
  const int m0 = mt << 7, n0 = nt << 8;
  const int NT = K >> 6;

  floatx4 acc[4][4];
#pragma unroll
  for (int i = 0; i < 4; ++i)
#pragma unroll
    for (int j = 0; j < 4; ++j) acc[i][j] = (floatx4){0.f, 0.f, 0.f, 0.f};
  bf16x8 af[4][2], b0[2][2], b1[2][2];

  // ---- staging: linear LDS dest, inverse-swizzled per-lane global source
  auto stA = [&](int buf, int kt) {
#pragma unroll
    for (int i = 0; i < 2; ++i) {
      int o = (i * 512 + t) * 16;                 // linear byte off in 16KB grp
      int os = o ^ (((o >> 7) & 7) << 4);         // element that lands here
      int rloc = os >> 7, kb = os & 127;
      const unsigned short* src = A + (size_t)(m0 + rloc) * lda + (kt << 6) + (kb >> 1);
      __builtin_amdgcn_global_load_lds(AS1(src), AS3(lds + buf * 16384 + o), 16, 0, 0);
    }
  };
  auto stBg = [&](int kt, int g) {
#pragma unroll
    for (int i = 0; i < 2; ++i) {
      int o = (i * 512 + t) * 16;
      int os = o ^ (((o >> 7) & 7) << 4);
      int rloc = os >> 7, kb = os & 127;
      int R = ((rloc >> 5) << 6) | (g << 5) | (rloc & 31);
      const unsigned short* src = B + (size_t)(n0 + R) * ldb + (kt << 6) + (kb >> 1);
      __builtin_amdgcn_global_load_lds(AS1(src),
          AS3(lds + 32768 + g * 16384 + o), 16, 0, 0);
    }
  };
  // ---- swizzled fragment reads
  auto rdA = [&](int buf, int mi, int ks) -> bf16x8 {
    int rloc = (wm << 6) | (mi << 4) | fr;
    return *(const bf16x8*)(lds + buf * 16384 + rloc * 128 +
                            (((ks << 6) | (quad << 4)) ^ ((fr & 7) << 4)));
  };
  auto rdB = [&](int ni, int ks) -> bf16x8 {
    int rloc = (wn << 5) | ((ni & 1) << 4) | fr;
    return *(const bf16x8*)(lds + 32768 + (ni >> 1) * 16384 + rloc * 128 +
                            (((ks << 6) | (quad << 4)) ^ ((fr & 7) << 4)));
  };

  // ---- prologue: A[0] + B.g0[0]; B.g1[0] is staged inside P1(0)
  stA(0, 0); stBg(0, 0);
  asm volatile("s_waitcnt vmcnt(0)" ::: "memory");
  __builtin_amdgcn_s_barrier();

  for (int kt = 0; kt < NT; ++kt) {
    const int buf = kt & 1;
    const bool pf = (kt + 1 < NT);
    // ---------------- phase 1 ----------------
#pragma unroll
    for (int mi = 0; mi < 4; ++mi) { af[mi][0] = rdA(buf, mi, 0); af[mi][1] = rdA(buf, mi, 1); }
#pragma unroll
    for (int ni = 0; ni < 2; ++ni) { b0[ni][0] = rdB(ni, 0); b0[ni][1] = rdB(ni, 1); }
    stBg(kt, 1);                       // Bg1[kt] (read in P2 this kt)
    if (pf) stA(buf ^ 1, kt + 1);
    asm volatile("s_waitcnt lgkmcnt(8)" ::: "memory");   // 12 ds_reads issued
    __builtin_amdgcn_s_barrier();
    asm volatile("s_waitcnt lgkmcnt(0)" ::: "memory");
    __builtin_amdgcn_s_setprio(1);
#pragma unroll
    for (int mi = 0; mi < 4; ++mi)
#pragma unroll
      for (int ni = 0; ni < 2; ++ni)
#pragma unroll
        for (int ks = 0; ks < 2; ++ks)
          acc[mi][ni] = __builtin_amdgcn_mfma_f32_16x16x32_bf16(af[mi][ks], b0[ni][ks], acc[mi][ni], 0, 0, 0);
    __builtin_amdgcn_s_setprio(0);
    if (pf) asm volatile("s_waitcnt vmcnt(2)" ::: "memory");  // Bg1[kt] landed
    else    asm volatile("s_waitcnt vmcnt(0)" ::: "memory");
    __builtin_amdgcn_s_barrier();
    // ---------------- phase 2 ----------------
#pragma unroll
    for (int ni = 0; ni < 2; ++ni) { b1[ni][0] = rdB(ni + 2, 0); b1[ni][1] = rdB(ni + 2, 1); }
    if (pf) stBg(kt + 1, 0);           // Bg0[kt+1] (g0 last read in P1(kt))
    __builtin_amdgcn_s_barrier();
    asm volatile("s_waitcnt lgkmcnt(0)" ::: "memory");
    __builtin_amdgcn_s_setprio(1);
#pragma unroll
    for (int mi = 0; mi < 4; ++mi)
#pragma unroll
      for (int ni = 0; ni < 2; ++ni)
#pragma unroll
        for (int ks = 0; ks < 2; ++ks)
          acc[mi][ni + 2] = __builtin_amdgcn_mfma_f32_16x16x32_bf16(af[mi][ks], b1[ni][ks], acc[mi][ni + 2], 0, 0, 0);
    __builtin_amdgcn_s_setprio(0);
    if (kt < NT - 1) {
      asm volatile("s_waitcnt vmcnt(0)" ::: "memory");  // A[kt+1]+Bg0[kt+1]
      __builtin_amdgcn_s_barrier();
    }
  }

  if (OMODE == 0) {
    // ---- epilogue: repack 128x256 bf16 through LDS, full-line stores
    __syncthreads();                   // all reads done before LDS reuse
    unsigned short* rp = (unsigned short*)lds;
    unsigned short* C = (unsigned short*)Cout;
    const int mb = wm * 64, nb = wn * 64;
#pragma unroll
    for (int mi = 0; mi < 4; ++mi)
#pragma unroll
      for (int ni = 0; ni < 4; ++ni)
#pragma unroll
        for (int r = 0; r < 4; ++r)
          rp[(mb + mi * 16 + quad * 4 + r) * 256 + nb + ni * 16 + fr] = f2bf(acc[mi][ni][r]);
    __syncthreads();
#pragma unroll
    for (int j = 0; j < 8; ++j) {
      int lin = j * 4096 + t * 8;
      int row = lin >> 8, col = lin & 255;
      int gcol = n0 + col;
      if (gcol < Nstore)
        *(u16x8*)&C[(size_t)(m0 + row) * ldc + gcol] = *(const u16x8*)&rp[lin];
    }
  } else {
    // ---- f32 direct frag stores: 16 consecutive lanes -> 64B segments
    float* Cf = (float*)Cout;
#pragma unroll
    for (int mi = 0; mi < 4; ++mi)
#pragma unroll
      for (int ni = 0; ni < 4; ++ni) {
        int gcol = n0 + wn * 64 + ni * 16 + fr;
        int grow = m0 + wm * 64 + mi * 16 + quad * 4;
#pragma unroll
        for (int r = 0; r < 4; ++r)
          if (gcol < Nstore)
            Cf[(size_t)(grow + r) * ldc + gcol] = acc[mi][ni][r];
      }
  }
}

// ---------------------------------------------------------------------------
// bf16 MFMA GEMM: C[m,n] = sum_k A[m,k]*B[n,k]  (K contiguous both operands)
// 128x128 tile, BK=32, 4 waves (2x2), 4x4 frags of 16x16x32 each.
// (Retained for MODE 1 (fused D-add, K=128) and MODE 2 (split-K).)
// ---------------------------------------------------------------------------
template <int MODE>
__global__ __launch_bounds__(256)
void gemm_bt_mfma(const unsigned short* __restrict__ A, int lda,
                  const unsigned short* __restrict__ B, int ldb,
                  void* __restrict__ Cout, int ldc,
                  int Kfull, int Nstore,
                  const unsigned short* __restrict__ xs,
                  const float* __restrict__ Dvec) {
  __shared__ __align__(16) char smem[17408];  // staging 16 KB; f32 repack 17 KB
  unsigned short* Asm = (unsigned short*)smem;
  unsigned short* Bsm = Asm + 128 * 32;
  const int t = threadIdx.x;

  int bx = blockIdx.x, by = blockIdx.y;
  if (MODE != 2) {
    int gx = gridDim.x;
    int linear = by * gx + bx;
    int xcd = linear & 7;
    int local = linear >> 3;
    by = xcd * 8 + (local & 7);
    bx = local >> 3;
  }
  const int m0 = by * 128;
  const int n0 = bx * 128;

  int kstart = 0, klen = Kfull;
  if (MODE == 2) { klen = Kfull / KSPLIT; kstart = blockIdx.z * klen; }
  const int wave = t >> 6, lane = t & 63;
  const int wm = (wave & 1) * 64;
  const int wn = (wave >> 1) * 64;
  const int fr = lane & 15;
  const int quad = lane >> 4;

  floatx4 acc[4][4];
#pragma unroll
  for (int i = 0; i < 4; ++i)
#pragma unroll
    for (int j = 0; j < 4; ++j) acc[i][j] = (floatx4){0.f, 0.f, 0.f, 0.f};

  for (int k0 = kstart; k0 < kstart + klen; k0 += 32) {
#pragma unroll
    for (int i = 0; i < 2; ++i) {
      int linear = i * 256 + t;          // 0..511
      int row = linear >> 2;             // 0..127
      int kq = (linear & 3) * 8;         // bf16 elem offset in K
      const unsigned short* ga = A + (size_t)(m0 + row) * lda + (k0 + kq);
      const unsigned short* gb = B + (size_t)(n0 + row) * ldb + (k0 + kq);
      __builtin_amdgcn_global_load_lds(AS1(ga), AS3(&Asm[linear * 8]), 16, 0, 0);
      __builtin_amdgcn_global_load_lds(AS1(gb), AS3(&Bsm[linear * 8]), 16, 0, 0);
    }
    __syncthreads();

    bf16x8 af[4], bfr[4];
#pragma unroll
    for (int i = 0; i < 4; ++i) {
      af[i]  = *(const bf16x8*)&Asm[(wm + i * 16 + fr) * 32 + quad * 8];
      bfr[i] = *(const bf16x8*)&Bsm[(wn + i * 16 + fr) * 32 + quad * 8];
    }
#pragma unroll
    for (int mi = 0; mi < 4; ++mi)
#pragma unroll
      for (int ni = 0; ni < 4; ++ni)
        acc[mi][ni] = __builtin_amdgcn_mfma_f32_16x16x32_bf16(
            af[mi], bfr[ni], acc[mi][ni], 0, 0, 0);
    __syncthreads();
  }

  // C/D frag layout: col = lane&15, row = (lane>>4)*4 + r  [m89-verified]
  const int lrbase = (wm ? 16 : 0) + quad * 4;
  if (MODE == 0 || MODE == 1) {
    unsigned short(*rp)[136] = (unsigned short(*)[136])smem;
    unsigned short* C = (unsigned short*)Cout;
#pragma unroll
    for (int mi = 0; mi < 4; ++mi) {
      __syncthreads();
#pragma unroll
      for (int ni = 0; ni < 4; ++ni)
#pragma unroll
        for (int r = 0; r < 4; ++r)
          rp[lrbase + r][wn + ni * 16 + fr] = f2bf(acc[mi][ni][r]);
      __syncthreads();
#pragma unroll
      for (int j = 0; j < 2; ++j) {
        int off = j * 2048 + t * 8;          // elem in 32x128 group
        int lr = off >> 7, c = off & 127;
        int grow = m0 + (lr >> 4) * 64 + mi * 16 + (lr & 15);
        int gcol = n0 + c;
        u16x8 v = *(const u16x8*)&rp[lr][c];
        if (MODE == 1) {
          u16x8 xv = *(const u16x8*)&xs[(size_t)grow * ldc + gcol];
          float Dh = Dvec[gcol >> 6];
          u16x8 o;
#pragma unroll
          for (int e = 0; e < 8; ++e) o[e] = f2bf(bf2f(v[e]) + Dh * bf2f(xv[e]));
          *(u16x8*)&C[(size_t)grow * ldc + gcol] = o;
        } else {
          if (gcol < Nstore) *(u16x8*)&C[(size_t)grow * ldc + gcol] = v;
        }
      }
    }
  } else {
    float(*rpf)[136] = (float(*)[136])smem;  // 32*136*4 = 17408 B
    float* C = (float*)Cout;
    if (MODE == 2) C += (size_t)blockIdx.z * DS * DI;
#pragma unroll
    for (int mi = 0; mi < 4; ++mi) {
      __syncthreads();
#pragma unroll
      for (int ni = 0; ni < 4; ++ni)
#pragma unroll
        for (int r = 0; r < 4; ++r)
          rpf[lrbase + r][wn + ni * 16 + fr] = acc[mi][ni][r];
      __syncthreads();
#pragma unroll
      for (int j = 0; j < 4; ++j) {
        int off = j * 1024 + t * 4;          // elem in 32x128 group
        int lr = off >> 7, c = off & 127;
        int grow = m0 + (lr >> 4) * 64 + mi * 16 + (lr & 15);
        int gcol = n0 + c;
        float4 v = *(const float4*)&rpf[lr][c];
        *(float4*)&C[(size_t)grow * ldc + gcol] = v;
      }
    }
  }
}

// ---------------------------------------------------------------------------
// One merged cast dispatch. Regions (in 256-thread blocks of 4-elem quads):
//   [0, 8192):        x       (8192x1024 f32 -> bf16)
//   [8192, 12800):    W_in    (4384x1024 -> 4608x1024 bf16, pad rows zero)
//   [12800, 14848):   W_out   (1024x2048 f32 -> bf16)
// ---------------------------------------------------------------------------
__global__ __launch_bounds__(256)
void cast_all_kernel(const float* __restrict__ x, const float* __restrict__ W_in,
                     const float* __restrict__ W_out,
                     unsigned short* __restrict__ x_bf16,
                     unsigned short* __restrict__ win_bf16,
                     unsigned short* __restrict__ wout_bf16) {
  int b = blockIdx.x;
  int t = threadIdx.x;
  u16x4 o = (u16x4){0, 0, 0, 0};
  if (b < 8192) {
    size_t i4 = ((size_t)b * 256 + t) * 4;
    float4 v = *(const float4*)(x + i4);
    o.x = f2bf(v.x); o.y = f2bf(v.y); o.z = f2bf(v.z); o.w = f2bf(v.w);
    *(u16x4*)(x_bf16 + i4) = o;
  } else if (b < 12800) {
    size_t i4 = ((size_t)(b - 8192) * 256 + t) * 4;  // over 4608*1024
    int row = (int)(i4 >> 10);
    if (row < DPROJ) {
      float4 v = *(const float4*)(W_in + i4);
      o.x = f2bf(v.x); o.y = f2bf(v.y); o.z = f2bf(v.z); o.w = f2bf(v.w);
    }
    *(u16x4*)(win_bf16 + i4) = o;
  } else {
    size_t i4 = ((size_t)(b - 12800) * 256 + t) * 4;
    float4 v = *(const float4*)(W_out + i4);
    o.x = f2bf(v.x); o.y = f2bf(v.y); o.z = f2bf(v.z); o.w = f2bf(v.w);
    *(u16x4*)(wout_bf16 + i4) = o;
  }
}

// ---------------------------------------------------------------------------
// s[l,h] = dt * exp(-dt*exp(A_log[h])),  dt = softplus(zxb[l,4352+h]+dt_bias[h])
// ---------------------------------------------------------------------------
__global__ __launch_bounds__(256)
void dt_kernel(const unsigned short* __restrict__ zxb, const float* __restrict__ dt_bias,
               const float* __restrict__ A_log, float* __restrict__ s_out) {
  int idx = blockIdx.x * 256 + threadIdx.x;  // l*32 + h
  int l = idx >> 5, h = idx & 31;
  float v = bf2f(zxb[(size_t)l * DPROJ + (DI + CDIM) + h]) + dt_bias[h];
  float d = (v > 20.f) ? v : log1pf(expf(v));
  s_out[idx] = d * expf(-d * expf(A_log[h]));
}

// ---------------------------------------------------------------------------
// Fused conv+silu+transpose. Block = 64 channels x 64 l, 256 threads.
// ---------------------------------------------------------------------------
__global__ __launch_bounds__(256)
void conv_fused_kernel(const unsigned short* __restrict__ zxb,
                       const float* __restrict__ Wc,
                       const float* __restrict__ bc,
                       const float* __restrict__ svec,
                       unsigned short* __restrict__ xs,
                       unsigned short* __restrict__ cb,
                       unsigned short* __restrict__ OpT) {
  __shared__ unsigned short zt[67][66];
  __shared__ unsigned short ot[64][66];
  __shared__ float sl[64];
  const int c0 = blockIdx.x * 64;
  const int l0 = blockIdx.y * 64;
  const int t = threadIdx.x;
  for (int idx = t; idx < 67 * 16; idx += 256) {
    int row = idx >> 4;
    int colq = (idx & 15) * 4;
    int gl = l0 - 1 + row;
    u16x4 v = (u16x4){0, 0, 0, 0};
    if (gl >= 0 && gl < L_SEQ)
      v = *(const u16x4*)&zxb[(size_t)gl * DPROJ + DI + c0 + colq];
    *(u16x4*)&zt[row][colq] = v;
  }
  const bool isX = (c0 < DI);
  const bool isC = (c0 >= DI + DS);
  if (isX && t < 64) sl[t] = svec[(size_t)(l0 + t) * NH + (c0 >> 6)];
  const int c = t & 63;
  const int gc = c0 + c;
  const float4 wv = *(const float4*)&Wc[gc * 4];
  const float bias = bc[gc];
  const int lq = (t >> 6) * 16;
  __syncthreads();
#pragma unroll
  for (int i = 0; i < 16; ++i) {
    int ll = lq + i;
    float sacc = bias + bf2f(zt[ll][c]) * wv.x + bf2f(zt[ll + 1][c]) * wv.y +
                 bf2f(zt[ll + 2][c]) * wv.z + bf2f(zt[ll + 3][c]) * wv.w;
    float v = sacc / (1.f + expf(-sacc));
    int gl = l0 + ll;
    if (isC) {
      cb[(size_t)gl * DS + (gc - (DI + DS))] = f2bf(v);
    } else if (isX) {
      xs[(size_t)gl * DI + gc] = f2bf(v);
      ot[c][ll] = f2bf(v * sl[ll]);
    } else {
      ot[c][ll] = f2bf(v);
    }
  }
  if (!isC) {
    __syncthreads();
#pragma unroll
    for (int j = 0; j < 4; ++j) {
      int linear = j * 1024 + t * 4;
      int rr = linear >> 6;
      int lc = linear & 63;
      *(u16x4*)&OpT[(size_t)(c0 + rr) * L_SEQ + l0 + lc] = *(const u16x4*)&ot[rr][lc];
    }
  }
}

// ---------------------------------------------------------------------------
// Ht[p][n] = bf16( sum_z Ppart[z][n][p] )
// ---------------------------------------------------------------------------
__global__ __launch_bounds__(256)
void h_reduce_t_kernel(const float* __restrict__ P, unsigned short* __restrict__ Ht) {
  __shared__ float tile[32][65];
  const int bid = blockIdx.x;
  const int pt = bid & 31, ng = bid >> 5;
  const int t = threadIdx.x;
#pragma unroll
  for (int i = 0; i < 8; ++i) {
    int nl = i * 4 + (t >> 6);
    int n = ng * 32 + nl;
    int p = pt * 64 + (t & 63);
    float acc = 0.f;
#pragma unroll
    for (int z = 0; z < KSPLIT; ++z)
      acc += P[(size_t)z * (DS * DI) + (size_t)n * DI + p];
    tile[nl][t & 63] = acc;
  }
  __syncthreads();
#pragma unroll
  for (int j = 0; j < 8; ++j) {
    int linear = j * 256 + t;
    int pl = linear >> 5, nl = linear & 31;
    Ht[(size_t)(pt * 64 + pl) * DS + ng * 32 + nl] = f2bf(tile[nl][pl]);
  }
}

// ---------------------------------------------------------------------------
// LayerNorm over 2048 (bf16 y) + z-gate (bf16 z); bf16 yz into zxb [2048,4096)
// ---------------------------------------------------------------------------
__global__ __launch_bounds__(256)
void ln_mul_kernel(const unsigned short* __restrict__ ybuf, unsigned short* __restrict__ zxb,
                   const float* __restrict__ ln_w, const float* __restrict__ ln_b) {
  int l = blockIdx.x;
  int t = threadIdx.x;
  int c0 = t * 8;
  u16x8 yv = *(const u16x8*)&ybuf[(size_t)l * DI + c0];
  float vals[8];
  float s = 0.f, sq = 0.f;
#pragma unroll
  for (int i = 0; i < 8; ++i) {
    float v = bf2f(yv[i]);
    vals[i] = v;
    s += v;
    sq += v * v;
  }
#pragma unroll
  for (int off = 32; off > 0; off >>= 1) {
    s += __shfl_down(s, off, 64);
    sq += __shfl_down(sq, off, 64);
  }
  __shared__ float red[10];
  int wave = t >> 6, lane = t & 63;
  if (lane == 0) { red[wave] = s; red[4 + wave] = sq; }
  __syncthreads();
  if (t == 0) {
    float S = red[0] + red[1] + red[2] + red[3];
    float SQ = red[4] + red[5] + red[6] + red[7];
    float mu = S / (float)DI;
    red[8] = mu;
    red[9] = rsqrtf(SQ / (float)DI - mu * mu + 1e-5f);
  }
  __syncthreads();
  float mu = red[8], rstd = red[9];
  unsigned short* zrow = zxb + (size_t)l * DPROJ;
  u16x8 zv = *(const u16x8*)&zrow[c0];
  float4 w0 = *(const float4*)&ln_w[c0], w1 = *(const float4*)&ln_w[c0 + 4];
  float4 b0 = *(const float4*)&ln_b[c0], b1 = *(const float4*)&ln_b[c0 + 4];
  float w[8] = {w0.x, w0.y, w0.z, w0.w, w1.x, w1.y, w1.z, w1.w};
  float b[8] = {b0.x, b0.y, b0.z, b0.w, b1.x, b1.y, b1.z, b1.w};
  u16x8 o;
#pragma unroll
  for (int i = 0; i < 8; ++i) {
    float v = (vals[i] - mu) * rstd * w[i] + b[i];
    o[i] = f2bf(v * bf2f(zv[i]));
  }
  *(u16x8*)&zrow[DI + c0] = o;
}

// ---------------------------------------------------------------------------
extern "C" void kernel_launch(void* const* d_in, const int* in_sizes, int n_in,
                              void* d_out, int out_size, void* d_ws, size_t ws_size,
                              hipStream_t stream) {
  const float* x       = (const float*)d_in[0];
  const float* W_in    = (const float*)d_in[1];
  const float* W_conv  = (const float*)d_in[2];
  const float* b_conv  = (const float*)d_in[3];
  const float* dt_bias = (const float*)d_in[4];
  const float* A_log   = (const float*)d_in[5];
  const float* D_param = (const float*)d_in[6];
  const float* ln_w    = (const float*)d_in[7];
  const float* ln_b    = (const float*)d_in[8];
  const float* W_out   = (const float*)d_in[9];
  float* out = (float*)d_out;

  // ---- workspace layout ----
  unsigned short* zxb = (unsigned short*)d_ws;           // L*4384 bf16
  unsigned short* xs   = zxb + (size_t)L_SEQ * DPROJ;    // L*2048 bf16
  unsigned short* cb   = xs + (size_t)L_SEQ * DI;        // L*128 bf16
  float* svec = (float*)(cb + (size_t)L_SEQ * DS);       // L*32 f32
  unsigned short* OpT = (unsigned short*)(svec + (size_t)L_SEQ * NH);  // 2176*8192 bf16
  float* Ppart = (float*)(OpT + (size_t)OPROWS * L_SEQ); // KSPLIT*128*2048 f32
  unsigned short* Ht = (unsigned short*)(Ppart + (size_t)KSPLIT * DS * DI);  // 2048*128
  unsigned short* wout_bf16 = Ht + (size_t)DI * DS;      // 1024*2048 bf16
  // aliases in OpT's dead windows:
  unsigned short* x_bf16   = OpT;                        // casts..GEMM1 (16 MB)
  unsigned short* win_bf16 = OpT + (size_t)L_SEQ * DM;   // casts..GEMM1 (9.4 MB)
  unsigned short* ybuf     = OpT;                        // Y-GEMM..ln_mul (33.5 MB)

  // 0) all casts in one dispatch
  cast_all_kernel<<<14848, 256, 0, stream>>>(x, W_in, W_out, x_bf16, win_bf16,
                                             wout_bf16);

  // 1) zxb = bf16( x @ W_in^T )  (M=8192, N=4608 pad, K=1024)
  //    128x256 ring, 64 KB LDS -> 2 blocks/CU; grid 18 x 64 = 1152 blocks
  gemm128_ring<0><<<dim3(NPAD_IN / 256, L_SEQ / 128), 512, 0, stream>>>(
      x_bf16, DM, win_bf16, DM, zxb, DPROJ, DM, DPROJ);

  // 2) s = a*dt
  dt_kernel<<<(L_SEQ * NH) / 256, 256, 0, stream>>>(zxb, dt_bias, A_log, svec);

  // 3) conv + silu + transpose-pack (clobbers x_bf16/win_bf16 — dead)
  conv_fused_kernel<<<dim3(CDIM / 64, L_SEQ / 64), 256, 0, stream>>>(
      zxb, W_conv, b_conv, svec, xs, cb, OpT);

  // 4) Hcat = B^T @ Vs : M=128, N=2048, K=8192, split-K=16 (256 blocks, f32 out)
  gemm_bt_mfma<2><<<dim3(DI / 128, 1, KSPLIT), 256, 0, stream>>>(
      OpT + (size_t)DI * L_SEQ, L_SEQ, OpT, L_SEQ, Ppart, DI, L_SEQ, DI,
      nullptr, nullptr);

  // 5) reduce partials + transpose -> Ht (2048 x 128 bf16)
  h_reduce_t_kernel<<<128, 256, 0, stream>>>(Ppart, Ht);

  // 6) y = C @ Hcat + D*x_ssm : M=8192, N=2048, K=128, bf16 repacked out
  gemm_bt_mfma<1><<<dim3(DI / 128, L_SEQ / 128), 256, 0, stream>>>(
      cb, DS, Ht, DS, ybuf, DI, DS, DI, xs, D_param);

  // 7) LN + z-gate -> bf16 yz into zxb cols [2048,4096)
  ln_mul_kernel<<<L_SEQ, 256, 0, stream>>>(ybuf, zxb, ln_w, ln_b);

  // 8) out = yz @ W_out^T : M=8192, N=1024, K=2048
  //    128x256 ring f32 out: grid 4 x 64 = 256 blocks
  gemm128_ring<1><<<dim3(DM / 256, L_SEQ / 128), 512, 0, stream>>>(
      zxb + DI, DPROJ, wout_bf16, DI, out, DM, DI, DM);
}

// Round 5
// 323.877 us; speedup vs baseline: 1.3301x; 1.3301x over previous
//
#include <hip/hip_runtime.h>
#include <hip/hip_bf16.h>
#include <math.h>

#define L_SEQ 8192
#define DM 1024
#define DI 2048
#define NH 32
#define HD 64
#define DS 128
#define CDIM 2304
#define DPROJ 4384
#define NPAD_IN 4608  // 36*128, zero-padded W_in rows
#define KSPLIT 16
#define OPROWS 2176   // 2048 Vs^T rows + 128 B^T rows

typedef short bf16x8 __attribute__((ext_vector_type(8)));
typedef float floatx4 __attribute__((ext_vector_type(4)));
typedef unsigned short u16x4 __attribute__((ext_vector_type(4)));
typedef unsigned short u16x8 __attribute__((ext_vector_type(8)));

#define AS1(p) ((const __attribute__((address_space(1))) void*)(p))
#define AS3(p) ((__attribute__((address_space(3))) void*)(p))

__device__ __forceinline__ float bf2f(unsigned short u) {
  union { unsigned int i; float f; } c; c.i = ((unsigned int)u) << 16; return c.f;
}
__device__ __forceinline__ unsigned short f2bf(float f) {
  return __bfloat16_as_ushort(__float2bfloat16(f));
}

// ---------------------------------------------------------------------------
// 128x128-tile TLP bf16 GEMM: 2 blocks/CU WITHOUT spilling (r4 post-mortem:
// ring spilled because acc[4][4]+operands ~150 VGPR > 128 cap; here per-wave
// output is 64x32 -> acc[4][2]=32 VGPR, total ~100 < 128).
// C[m,n] = sum_k A[m,k]*B[n,k]. 512 thr = 8 waves (2M x 4N), BK=64, NT=K/64
// (NT>=2 required). LDS 64 KB: A[2][128][64] + B[2][128][64] bf16 (16KB grps).
// Swizzle (rule #21 both-sides): byte ^= ((byte>>7)&7)<<4 within each 16KB
//   group; LDS dest LINEAR (gload_lds), involution on per-lane GLOBAL source
//   and again on ds_read addr. 2-way-only bank aliasing on ds_read_b128.
// Schedule per kt (buf=kt&1), 2 phases:
//   P1: read af(8)+b0(2); stage B[kt+1]->buf^1; bar; lgkm(0); prio1;
//       8 MFMA (ni=0); prio0; bar                      (no vm wait)
//   P2: read b1(2); stage A[kt+2]->buf; bar; lgkm(0); prio1;
//       8 MFMA (ni=1); prio0; vmcnt(2)|vmcnt(0); bar
// Slot hazards: stB(buf^1,kt+1) overwrites B[kt-1], last read P2(kt-1)
//   (lgkm-complete before its trailing bar) -> >=1 barrier. SAFE.
//   stA(buf,kt+2) overwrites A[kt], last read P1(kt), >=1 barrier. SAFE.
// vmcnt ledger (2 instr per stage): prologue stages A0,B0,A1, vmcnt(2)
//   drains A0,B0. P1(kt): +B[kt+1] -> 4 outst. P2(kt): +A[kt+2] -> 6;
//   end-P2 vmcnt(2) drains oldest 4 = {A[kt+1],B[kt+1]} = exactly P1(kt+1)'s
//   inputs, leaves A[kt+2]. Tail: pfA false -> no stage, vmcnt(0).
// OMODE 0: bf16 out via LDS repack (32KB), Nstore guard (8-col runs).
// OMODE 1: f32 out, direct frag stores (16-lane 64B segments).
// ---------------------------------------------------------------------------
template <int OMODE>
__global__ __launch_bounds__(512, 4)
void gemm128_tlp(const unsigned short* __restrict__ A, int lda,
                 const unsigned short* __restrict__ B, int ldb,
                 void* __restrict__ Cout, int ldc,
                 int K, int Nstore) {
  __shared__ __align__(16) char lds[65536];
  const int t = threadIdx.x;
  const int lane = t & 63;
  const int w = t >> 6;
  const int wm = w & 1, wn = w >> 1;
  const int fr = lane & 15, quad = lane >> 4;

  // bijective XCD swizzle: xcd owns a contiguous m-band, m-fastest within n
  int gx = gridDim.x, gy = gridDim.y;
  int linear = blockIdx.y * gx + blockIdx.x;
  int xcd = linear & 7, loc = linear >> 3;
  int mper = gy >> 3;                       // gy must be %8==0 (64 here)
  int mt = xcd * mper + loc % mper;
  int nt = loc / mper;
  const int m0 = mt << 7, n0 = nt << 7;
  const int NT = K >> 6;

  floatx4 acc[4][2];
#pragma unroll
  for (int i = 0; i < 4; ++i)
#pragma unroll
    for (int j = 0; j < 2; ++j) acc[i][j] = (floatx4){0.f, 0.f, 0.f, 0.f};
  bf16x8 af[4][2], b0[2], b1[2];

  // ---- staging: linear LDS dest, inverse-swizzled per-lane global source
  auto stA = [&](int buf, int kt) {
#pragma unroll
    for (int i = 0; i < 2; ++i) {
      int o = (i * 512 + t) * 16;                 // linear byte off in 16KB grp
      int os = o ^ (((o >> 7) & 7) << 4);         // element that lands here
      int rloc = os >> 7, kb = os & 127;
      const unsigned short* src = A + (size_t)(m0 + rloc) * lda + (kt << 6) + (kb >> 1);
      __builtin_amdgcn_global_load_lds(AS1(src), AS3(lds + buf * 16384 + o), 16, 0, 0);
    }
  };
  auto stB = [&](int buf, int kt) {
#pragma unroll
    for (int i = 0; i < 2; ++i) {
      int o = (i * 512 + t) * 16;
      int os = o ^ (((o >> 7) & 7) << 4);
      int rloc = os >> 7, kb = os & 127;
      const unsigned short* src = B + (size_t)(n0 + rloc) * ldb + (kt << 6) + (kb >> 1);
      __builtin_amdgcn_global_load_lds(AS1(src),
          AS3(lds + 32768 + buf * 16384 + o), 16, 0, 0);
    }
  };
  // ---- swizzled fragment reads
  auto rdA = [&](int buf, int mi, int ks) -> bf16x8 {
    int rloc = (wm << 6) | (mi << 4) | fr;
    return *(const bf16x8*)(lds + buf * 16384 + rloc * 128 +
                            (((ks << 6) | (quad << 4)) ^ ((fr & 7) << 4)));
  };
  auto rdB = [&](int buf, int ni, int ks) -> bf16x8 {
    int rloc = (wn << 5) | (ni << 4) | fr;
    return *(const bf16x8*)(lds + 32768 + buf * 16384 + rloc * 128 +
                            (((ks << 6) | (quad << 4)) ^ ((fr & 7) << 4)));
  };

  // ---- prologue: A0,B0 + A1; B1 staged inside P1(0)
  stA(0, 0); stB(0, 0);
  if (NT > 1) {
    stA(1, 1);
    asm volatile("s_waitcnt vmcnt(2)" ::: "memory");   // A0,B0 landed
  } else {
    asm volatile("s_waitcnt vmcnt(0)" ::: "memory");
  }
  __builtin_amdgcn_s_barrier();

  for (int kt = 0; kt < NT; ++kt) {
    const int buf = kt & 1;
    const bool pfB = (kt + 1 < NT);
    const bool pfA = (kt + 2 < NT);
    // ---------------- phase 1 (ni = 0) ----------------
#pragma unroll
    for (int mi = 0; mi < 4; ++mi) { af[mi][0] = rdA(buf, mi, 0); af[mi][1] = rdA(buf, mi, 1); }
    b0[0] = rdB(buf, 0, 0); b0[1] = rdB(buf, 0, 1);
    if (pfB) stB(buf ^ 1, kt + 1);
    __builtin_amdgcn_s_barrier();
    asm volatile("s_waitcnt lgkmcnt(0)" ::: "memory");
    __builtin_amdgcn_s_setprio(1);
#pragma unroll
    for (int mi = 0; mi < 4; ++mi)
#pragma unroll
      for (int ks = 0; ks < 2; ++ks)
        acc[mi][0] = __builtin_amdgcn_mfma_f32_16x16x32_bf16(af[mi][ks], b0[ks], acc[mi][0], 0, 0, 0);
    __builtin_amdgcn_s_setprio(0);
    __builtin_amdgcn_s_barrier();
    // ---------------- phase 2 (ni = 1) ----------------
    b1[0] = rdB(buf, 1, 0); b1[1] = rdB(buf, 1, 1);
    if (pfA) stA(buf, kt + 2);
    __builtin_amdgcn_s_barrier();
    asm volatile("s_waitcnt lgkmcnt(0)" ::: "memory");
    __builtin_amdgcn_s_setprio(1);
#pragma unroll
    for (int mi = 0; mi < 4; ++mi)
#pragma unroll
      for (int ks = 0; ks < 2; ++ks)
        acc[mi][1] = __builtin_amdgcn_mfma_f32_16x16x32_bf16(af[mi][ks], b1[ks], acc[mi][1], 0, 0, 0);
    __builtin_amdgcn_s_setprio(0);
    if (kt < NT - 1) {
      if (pfA) asm volatile("s_waitcnt vmcnt(2)" ::: "memory");  // {A,B}[kt+1]
      else     asm volatile("s_waitcnt vmcnt(0)" ::: "memory");
      __builtin_amdgcn_s_barrier();
    }
  }

  if (OMODE == 0) {
    // ---- epilogue: repack 128x128 bf16 through LDS, full-line stores
    __syncthreads();                   // all LDS reads done before reuse
    unsigned short* rp = (unsigned short*)lds;
    unsigned short* C = (unsigned short*)Cout;
    const int mb = wm * 64, nb = wn * 32;
#pragma unroll
    for (int mi = 0; mi < 4; ++mi)
#pragma unroll
      for (int ni = 0; ni < 2; ++ni)
#pragma unroll
        for (int r = 0; r < 4; ++r)
          rp[(mb + mi * 16 + quad * 4 + r) * 128 + nb + ni * 16 + fr] = f2bf(acc[mi][ni][r]);
    __syncthreads();
#pragma unroll
    for (int j = 0; j < 4; ++j) {
      int lin = j * 4096 + t * 8;
      int row = lin >> 7, col = lin & 127;
      int gcol = n0 + col;
      if (gcol < Nstore)
        *(u16x8*)&C[(size_t)(m0 + row) * ldc + gcol] = *(const u16x8*)&rp[lin];
    }
  } else {
    // ---- f32 direct frag stores: 16 consecutive lanes -> 64B segments
    float* Cf = (float*)Cout;
#pragma unroll
    for (int mi = 0; mi < 4; ++mi)
#pragma unroll
      for (int ni = 0; ni < 2; ++ni) {
        int gcol = n0 + wn * 32 + ni * 16 + fr;
        int grow = m0 + wm * 64 + mi * 16 + quad * 4;
#pragma unroll
        for (int r = 0; r < 4; ++r)
          if (gcol < Nstore)
            Cf[(size_t)(grow + r) * ldc + gcol] = acc[mi][ni][r];
      }
  }
}

// ---------------------------------------------------------------------------
// bf16 MFMA GEMM: C[m,n] = sum_k A[m,k]*B[n,k]  (K contiguous both operands)
// 128x128 tile, BK=32, 4 waves (2x2), 4x4 frags of 16x16x32 each.
// (Retained for MODE 1 (fused D-add, K=128) and MODE 2 (split-K).)
// ---------------------------------------------------------------------------
template <int MODE>
__global__ __launch_bounds__(256)
void gemm_bt_mfma(const unsigned short* __restrict__ A, int lda,
                  const unsigned short* __restrict__ B, int ldb,
                  void* __restrict__ Cout, int ldc,
                  int Kfull, int Nstore,
                  const unsigned short* __restrict__ xs,
                  const float* __restrict__ Dvec) {
  __shared__ __align__(16) char smem[17408];  // staging 16 KB; f32 repack 17 KB
  unsigned short* Asm = (unsigned short*)smem;
  unsigned short* Bsm = Asm + 128 * 32;
  const int t = threadIdx.x;

  int bx = blockIdx.x, by = blockIdx.y;
  if (MODE != 2) {
    int gx = gridDim.x;
    int linear = by * gx + bx;
    int xcd = linear & 7;
    int local = linear >> 3;
    by = xcd * 8 + (local & 7);
    bx = local >> 3;
  }
  const int m0 = by * 128;
  const int n0 = bx * 128;

  int kstart = 0, klen = Kfull;
  if (MODE == 2) { klen = Kfull / KSPLIT; kstart = blockIdx.z * klen; }
  const int wave = t >> 6, lane = t & 63;
  const int wm = (wave & 1) * 64;
  const int wn = (wave >> 1) * 64;
  const int fr = lane & 15;
  const int quad = lane >> 4;

  floatx4 acc[4][4];
#pragma unroll
  for (int i = 0; i < 4; ++i)
#pragma unroll
    for (int j = 0; j < 4; ++j) acc[i][j] = (floatx4){0.f, 0.f, 0.f, 0.f};

  for (int k0 = kstart; k0 < kstart + klen; k0 += 32) {
#pragma unroll
    for (int i = 0; i < 2; ++i) {
      int linear = i * 256 + t;          // 0..511
      int row = linear >> 2;             // 0..127
      int kq = (linear & 3) * 8;         // bf16 elem offset in K
      const unsigned short* ga = A + (size_t)(m0 + row) * lda + (k0 + kq);
      const unsigned short* gb = B + (size_t)(n0 + row) * ldb + (k0 + kq);
      __builtin_amdgcn_global_load_lds(AS1(ga), AS3(&Asm[linear * 8]), 16, 0, 0);
      __builtin_amdgcn_global_load_lds(AS1(gb), AS3(&Bsm[linear * 8]), 16, 0, 0);
    }
    __syncthreads();

    bf16x8 af[4], bfr[4];
#pragma unroll
    for (int i = 0; i < 4; ++i) {
      af[i]  = *(const bf16x8*)&Asm[(wm + i * 16 + fr) * 32 + quad * 8];
      bfr[i] = *(const bf16x8*)&Bsm[(wn + i * 16 + fr) * 32 + quad * 8];
    }
#pragma unroll
    for (int mi = 0; mi < 4; ++mi)
#pragma unroll
      for (int ni = 0; ni < 4; ++ni)
        acc[mi][ni] = __builtin_amdgcn_mfma_f32_16x16x32_bf16(
            af[mi], bfr[ni], acc[mi][ni], 0, 0, 0);
    __syncthreads();
  }

  // C/D frag layout: col = lane&15, row = (lane>>4)*4 + r  [m89-verified]
  const int lrbase = (wm ? 16 : 0) + quad * 4;
  if (MODE == 0 || MODE == 1) {
    unsigned short(*rp)[136] = (unsigned short(*)[136])smem;
    unsigned short* C = (unsigned short*)Cout;
#pragma unroll
    for (int mi = 0; mi < 4; ++mi) {
      __syncthreads();
#pragma unroll
      for (int ni = 0; ni < 4; ++ni)
#pragma unroll
        for (int r = 0; r < 4; ++r)
          rp[lrbase + r][wn + ni * 16 + fr] = f2bf(acc[mi][ni][r]);
      __syncthreads();
#pragma unroll
      for (int j = 0; j < 2; ++j) {
        int off = j * 2048 + t * 8;          // elem in 32x128 group
        int lr = off >> 7, c = off & 127;
        int grow = m0 + (lr >> 4) * 64 + mi * 16 + (lr & 15);
        int gcol = n0 + c;
        u16x8 v = *(const u16x8*)&rp[lr][c];
        if (MODE == 1) {
          u16x8 xv = *(const u16x8*)&xs[(size_t)grow * ldc + gcol];
          float Dh = Dvec[gcol >> 6];
          u16x8 o;
#pragma unroll
          for (int e = 0; e < 8; ++e) o[e] = f2bf(bf2f(v[e]) + Dh * bf2f(xv[e]));
          *(u16x8*)&C[(size_t)grow * ldc + gcol] = o;
        } else {
          if (gcol < Nstore) *(u16x8*)&C[(size_t)grow * ldc + gcol] = v;
        }
      }
    }
  } else {
    float(*rpf)[136] = (float(*)[136])smem;  // 32*136*4 = 17408 B
    float* C = (float*)Cout;
    if (MODE == 2) C += (size_t)blockIdx.z * DS * DI;
#pragma unroll
    for (int mi = 0; mi < 4; ++mi) {
      __syncthreads();
#pragma unroll
      for (int ni = 0; ni < 4; ++ni)
#pragma unroll
        for (int r = 0; r < 4; ++r)
          rpf[lrbase + r][wn + ni * 16 + fr] = acc[mi][ni][r];
      __syncthreads();
#pragma unroll
      for (int j = 0; j < 4; ++j) {
        int off = j * 1024 + t * 4;          // elem in 32x128 group
        int lr = off >> 7, c = off & 127;
        int grow = m0 + (lr >> 4) * 64 + mi * 16 + (lr & 15);
        int gcol = n0 + c;
        float4 v = *(const float4*)&rpf[lr][c];
        *(float4*)&C[(size_t)grow * ldc + gcol] = v;
      }
    }
  }
}

// ---------------------------------------------------------------------------
// One merged cast dispatch. Regions (in 256-thread blocks of 4-elem quads):
//   [0, 8192):        x       (8192x1024 f32 -> bf16)
//   [8192, 12800):    W_in    (4384x1024 -> 4608x1024 bf16, pad rows zero)
//   [12800, 14848):   W_out   (1024x2048 f32 -> bf16)
// ---------------------------------------------------------------------------
__global__ __launch_bounds__(256)
void cast_all_kernel(const float* __restrict__ x, const float* __restrict__ W_in,
                     const float* __restrict__ W_out,
                     unsigned short* __restrict__ x_bf16,
                     unsigned short* __restrict__ win_bf16,
                     unsigned short* __restrict__ wout_bf16) {
  int b = blockIdx.x;
  int t = threadIdx.x;
  u16x4 o = (u16x4){0, 0, 0, 0};
  if (b < 8192) {
    size_t i4 = ((size_t)b * 256 + t) * 4;
    float4 v = *(const float4*)(x + i4);
    o.x = f2bf(v.x); o.y = f2bf(v.y); o.z = f2bf(v.z); o.w = f2bf(v.w);
    *(u16x4*)(x_bf16 + i4) = o;
  } else if (b < 12800) {
    size_t i4 = ((size_t)(b - 8192) * 256 + t) * 4;  // over 4608*1024
    int row = (int)(i4 >> 10);
    if (row < DPROJ) {
      float4 v = *(const float4*)(W_in + i4);
      o.x = f2bf(v.x); o.y = f2bf(v.y); o.z = f2bf(v.z); o.w = f2bf(v.w);
    }
    *(u16x4*)(win_bf16 + i4) = o;
  } else {
    size_t i4 = ((size_t)(b - 12800) * 256 + t) * 4;
    float4 v = *(const float4*)(W_out + i4);
    o.x = f2bf(v.x); o.y = f2bf(v.y); o.z = f2bf(v.z); o.w = f2bf(v.w);
    *(u16x4*)(wout_bf16 + i4) = o;
  }
}

// ---------------------------------------------------------------------------
// s[l,h] = dt * exp(-dt*exp(A_log[h])),  dt = softplus(zxb[l,4352+h]+dt_bias[h])
// ---------------------------------------------------------------------------
__global__ __launch_bounds__(256)
void dt_kernel(const unsigned short* __restrict__ zxb, const float* __restrict__ dt_bias,
               const float* __restrict__ A_log, float* __restrict__ s_out) {
  int idx = blockIdx.x * 256 + threadIdx.x;  // l*32 + h
  int l = idx >> 5, h = idx & 31;
  float v = bf2f(zxb[(size_t)l * DPROJ + (DI + CDIM) + h]) + dt_bias[h];
  float d = (v > 20.f) ? v : log1pf(expf(v));
  s_out[idx] = d * expf(-d * expf(A_log[h]));
}

// ---------------------------------------------------------------------------
// Fused conv+silu+transpose. Block = 64 channels x 64 l, 256 threads.
// ---------------------------------------------------------------------------
__global__ __launch_bounds__(256)
void conv_fused_kernel(const unsigned short* __restrict__ zxb,
                       const float* __restrict__ Wc,
                       const float* __restrict__ bc,
                       const float* __restrict__ svec,
                       unsigned short* __restrict__ xs,
                       unsigned short* __restrict__ cb,
                       unsigned short* __restrict__ OpT) {
  __shared__ unsigned short zt[67][66];
  __shared__ unsigned short ot[64][66];
  __shared__ float sl[64];
  const int c0 = blockIdx.x * 64;
  const int l0 = blockIdx.y * 64;
  const int t = threadIdx.x;
  for (int idx = t; idx < 67 * 16; idx += 256) {
    int row = idx >> 4;
    int colq = (idx & 15) * 4;
    int gl = l0 - 1 + row;
    u16x4 v = (u16x4){0, 0, 0, 0};
    if (gl >= 0 && gl < L_SEQ)
      v = *(const u16x4*)&zxb[(size_t)gl * DPROJ + DI + c0 + colq];
    *(u16x4*)&zt[row][colq] = v;
  }
  const bool isX = (c0 < DI);
  const bool isC = (c0 >= DI + DS);
  if (isX && t < 64) sl[t] = svec[(size_t)(l0 + t) * NH + (c0 >> 6)];
  const int c = t & 63;
  const int gc = c0 + c;
  const float4 wv = *(const float4*)&Wc[gc * 4];
  const float bias = bc[gc];
  const int lq = (t >> 6) * 16;
  __syncthreads();
#pragma unroll
  for (int i = 0; i < 16; ++i) {
    int ll = lq + i;
    float sacc = bias + bf2f(zt[ll][c]) * wv.x + bf2f(zt[ll + 1][c]) * wv.y +
                 bf2f(zt[ll + 2][c]) * wv.z + bf2f(zt[ll + 3][c]) * wv.w;
    float v = sacc / (1.f + expf(-sacc));
    int gl = l0 + ll;
    if (isC) {
      cb[(size_t)gl * DS + (gc - (DI + DS))] = f2bf(v);
    } else if (isX) {
      xs[(size_t)gl * DI + gc] = f2bf(v);
      ot[c][ll] = f2bf(v * sl[ll]);
    } else {
      ot[c][ll] = f2bf(v);
    }
  }
  if (!isC) {
    __syncthreads();
#pragma unroll
    for (int j = 0; j < 4; ++j) {
      int linear = j * 1024 + t * 4;
      int rr = linear >> 6;
      int lc = linear & 63;
      *(u16x4*)&OpT[(size_t)(c0 + rr) * L_SEQ + l0 + lc] = *(const u16x4*)&ot[rr][lc];
    }
  }
}

// ---------------------------------------------------------------------------
// Ht[p][n] = bf16( sum_z Ppart[z][n][p] )
// ---------------------------------------------------------------------------
__global__ __launch_bounds__(256)
void h_reduce_t_kernel(const float* __restrict__ P, unsigned short* __restrict__ Ht) {
  __shared__ float tile[32][65];
  const int bid = blockIdx.x;
  const int pt = bid & 31, ng = bid >> 5;
  const int t = threadIdx.x;
#pragma unroll
  for (int i = 0; i < 8; ++i) {
    int nl = i * 4 + (t >> 6);
    int n = ng * 32 + nl;
    int p = pt * 64 + (t & 63);
    float acc = 0.f;
#pragma unroll
    for (int z = 0; z < KSPLIT; ++z)
      acc += P[(size_t)z * (DS * DI) + (size_t)n * DI + p];
    tile[nl][t & 63] = acc;
  }
  __syncthreads();
#pragma unroll
  for (int j = 0; j < 8; ++j) {
    int linear = j * 256 + t;
    int pl = linear >> 5, nl = linear & 31;
    Ht[(size_t)(pt * 64 + pl) * DS + ng * 32 + nl] = f2bf(tile[nl][pl]);
  }
}

// ---------------------------------------------------------------------------
// LayerNorm over 2048 (bf16 y) + z-gate (bf16 z); bf16 yz into zxb [2048,4096)
// ---------------------------------------------------------------------------
__global__ __launch_bounds__(256)
void ln_mul_kernel(const unsigned short* __restrict__ ybuf, unsigned short* __restrict__ zxb,
                   const float* __restrict__ ln_w, const float* __restrict__ ln_b) {
  int l = blockIdx.x;
  int t = threadIdx.x;
  int c0 = t * 8;
  u16x8 yv = *(const u16x8*)&ybuf[(size_t)l * DI + c0];
  float vals[8];
  float s = 0.f, sq = 0.f;
#pragma unroll
  for (int i = 0; i < 8; ++i) {
    float v = bf2f(yv[i]);
    vals[i] = v;
    s += v;
    sq += v * v;
  }
#pragma unroll
  for (int off = 32; off > 0; off >>= 1) {
    s += __shfl_down(s, off, 64);
    sq += __shfl_down(sq, off, 64);
  }
  __shared__ float red[10];
  int wave = t >> 6, lane = t & 63;
  if (lane == 0) { red[wave] = s; red[4 + wave] = sq; }
  __syncthreads();
  if (t == 0) {
    float S = red[0] + red[1] + red[2] + red[3];
    float SQ = red[4] + red[5] + red[6] + red[7];
    float mu = S / (float)DI;
    red[8] = mu;
    red[9] = rsqrtf(SQ / (float)DI - mu * mu + 1e-5f);
  }
  __syncthreads();
  float mu = red[8], rstd = red[9];
  unsigned short* zrow = zxb + (size_t)l * DPROJ;
  u16x8 zv = *(const u16x8*)&zrow[c0];
  float4 w0 = *(const float4*)&ln_w[c0], w1 = *(const float4*)&ln_w[c0 + 4];
  float4 b0 = *(const float4*)&ln_b[c0], b1 = *(const float4*)&ln_b[c0 + 4];
  float w[8] = {w0.x, w0.y, w0.z, w0.w, w1.x, w1.y, w1.z, w1.w};
  float b[8] = {b0.x, b0.y, b0.z, b0.w, b1.x, b1.y, b1.z, b1.w};
  u16x8 o;
#pragma unroll
  for (int i = 0; i < 8; ++i) {
    float v = (vals[i] - mu) * rstd * w[i] + b[i];
    o[i] = f2bf(v * bf2f(zv[i]));
  }
  *(u16x8*)&zrow[DI + c0] = o;
}

// ---------------------------------------------------------------------------
extern "C" void kernel_launch(void* const* d_in, const int* in_sizes, int n_in,
                              void* d_out, int out_size, void* d_ws, size_t ws_size,
                              hipStream_t stream) {
  const float* x       = (const float*)d_in[0];
  const float* W_in    = (const float*)d_in[1];
  const float* W_conv  = (const float*)d_in[2];
  const float* b_conv  = (const float*)d_in[3];
  const float* dt_bias = (const float*)d_in[4];
  const float* A_log   = (const float*)d_in[5];
  const float* D_param = (const float*)d_in[6];
  const float* ln_w    = (const float*)d_in[7];
  const float* ln_b    = (const float*)d_in[8];
  const float* W_out   = (const float*)d_in[9];
  float* out = (float*)d_out;

  // ---- workspace layout ----
  unsigned short* zxb = (unsigned short*)d_ws;           // L*4384 bf16
  unsigned short* xs   = zxb + (size_t)L_SEQ * DPROJ;    // L*2048 bf16
  unsigned short* cb   = xs + (size_t)L_SEQ * DI;        // L*128 bf16
  float* svec = (float*)(cb + (size_t)L_SEQ * DS);       // L*32 f32
  unsigned short* OpT = (unsigned short*)(svec + (size_t)L_SEQ * NH);  // 2176*8192 bf16
  float* Ppart = (float*)(OpT + (size_t)OPROWS * L_SEQ); // KSPLIT*128*2048 f32
  unsigned short* Ht = (unsigned short*)(Ppart + (size_t)KSPLIT * DS * DI);  // 2048*128
  unsigned short* wout_bf16 = Ht + (size_t)DI * DS;      // 1024*2048 bf16
  // aliases in OpT's dead windows:
  unsigned short* x_bf16   = OpT;                        // casts..GEMM1 (16 MB)
  unsigned short* win_bf16 = OpT + (size_t)L_SEQ * DM;   // casts..GEMM1 (9.4 MB)
  unsigned short* ybuf     = OpT;                        // Y-GEMM..ln_mul (33.5 MB)

  // 0) all casts in one dispatch
  cast_all_kernel<<<14848, 256, 0, stream>>>(x, W_in, W_out, x_bf16, win_bf16,
                                             wout_bf16);

  // 1) zxb = bf16( x @ W_in^T )  (M=8192, N=4608 pad, K=1024)
  //    128x128 TLP, 64 KB LDS + ~100 VGPR -> 2 blocks/CU; grid 36x64
  gemm128_tlp<0><<<dim3(NPAD_IN / 128, L_SEQ / 128), 512, 0, stream>>>(
      x_bf16, DM, win_bf16, DM, zxb, DPROJ, DM, DPROJ);

  // 2) s = a*dt
  dt_kernel<<<(L_SEQ * NH) / 256, 256, 0, stream>>>(zxb, dt_bias, A_log, svec);

  // 3) conv + silu + transpose-pack (clobbers x_bf16/win_bf16 — dead)
  conv_fused_kernel<<<dim3(CDIM / 64, L_SEQ / 64), 256, 0, stream>>>(
      zxb, W_conv, b_conv, svec, xs, cb, OpT);

  // 4) Hcat = B^T @ Vs : M=128, N=2048, K=8192, split-K=16 (256 blocks, f32 out)
  gemm_bt_mfma<2><<<dim3(DI / 128, 1, KSPLIT), 256, 0, stream>>>(
      OpT + (size_t)DI * L_SEQ, L_SEQ, OpT, L_SEQ, Ppart, DI, L_SEQ, DI,
      nullptr, nullptr);

  // 5) reduce partials + transpose -> Ht (2048 x 128 bf16)
  h_reduce_t_kernel<<<128, 256, 0, stream>>>(Ppart, Ht);

  // 6) y = C @ Hcat + D*x_ssm : M=8192, N=2048, K=128, bf16 repacked out
  gemm_bt_mfma<1><<<dim3(DI / 128, L_SEQ / 128), 256, 0, stream>>>(
      cb, DS, Ht, DS, ybuf, DI, DS, DI, xs, D_param);

  // 7) LN + z-gate -> bf16 yz into zxb cols [2048,4096)
  ln_mul_kernel<<<L_SEQ, 256, 0, stream>>>(ybuf, zxb, ln_w, ln_b);

  // 8) out = yz @ W_out^T : M=8192, N=1024, K=2048
  //    128x128 TLP f32 out: grid 8 x 64 = 512 blocks = exactly 1 round at 2/CU
  gemm128_tlp<1><<<dim3(DM / 128, L_SEQ / 128), 512, 0, stream>>>(
      zxb + DI, DPROJ, wout_bf16, DI, out, DM, DI, DM);
}